// Round 7
// baseline (263.242 us; speedup 1.0000x reference)
//
#include <hip/hip_runtime.h>
#include <stdint.h>
#include <stddef.h>

#define B_ 2
#define T_ 2048
#define D_ 1024
#define H_ 16
#define U_ 64
#define M_ (B_ * T_)   // 4096
#define N_ (H_ * U_)   // 1024

typedef __attribute__((ext_vector_type(4))) float f32x4;
typedef __attribute__((ext_vector_type(8))) short s16x8;
typedef __attribute__((ext_vector_type(8))) __bf16 b16x8;

static_assert(sizeof(s16x8) == 16, "frag size");

__device__ __forceinline__ unsigned short f2bf(float f) {
  unsigned int u = __float_as_uint(f);
  u += 0x7FFFu + ((u >> 16) & 1u);     // RNE
  return (unsigned short)(u >> 16);
}

// --- MFMA wrapper: SFINAE hedge — works whether the builtin takes short8 or bf16x8
template <typename V>
__device__ __forceinline__ auto mfma16_impl(V a, V b, f32x4 c, int)
    -> decltype(__builtin_amdgcn_mfma_f32_16x16x32_bf16(a, b, c, 0, 0, 0)) {
  return __builtin_amdgcn_mfma_f32_16x16x32_bf16(a, b, c, 0, 0, 0);
}
template <typename V>
__device__ __forceinline__ f32x4 mfma16_impl(V a, V b, f32x4 c, long) {
  return __builtin_amdgcn_mfma_f32_16x16x32_bf16(
      __builtin_bit_cast(b16x8, a), __builtin_bit_cast(b16x8, b), c, 0, 0, 0);
}
__device__ __forceinline__ f32x4 mfma16(s16x8 a, s16x8 b, f32x4 c) {
  return mfma16_impl(a, b, c, 0);
}

// --- async global->LDS, 16B per lane (m97 lever)
__device__ __forceinline__ void gld16(const unsigned short* g, unsigned short* l) {
  __builtin_amdgcn_global_load_lds(
      (const __attribute__((address_space(1))) void*)g,
      (__attribute__((address_space(3))) void*)l, 16, 0, 0);
}

// ---------------------------------------------------------------- K0: W -> W^T (bf16)
__global__ void wtrans_kernel(const float* __restrict__ w0, const float* __restrict__ w1,
                              const float* __restrict__ w2, const float* __restrict__ w3,
                              unsigned short* __restrict__ o0, unsigned short* __restrict__ o1,
                              unsigned short* __restrict__ o2, unsigned short* __restrict__ o3) {
  __shared__ float tile[64][65];
  const float* w;
  unsigned short* o;
  switch (blockIdx.z) {
    case 0: w = w0; o = o0; break;
    case 1: w = w1; o = o1; break;
    case 2: w = w2; o = o2; break;
    default: w = w3; o = o3; break;
  }
  const int kb = blockIdx.y * 64, nb = blockIdx.x * 64;
  const int tid = threadIdx.x;
  const int r0 = tid >> 6, c = tid & 63;
#pragma unroll
  for (int i = 0; i < 16; i++) {
    int r = i * 4 + r0;
    tile[r][c] = w[(size_t)(kb + r) * 1024 + nb + c];
  }
  __syncthreads();
#pragma unroll
  for (int i = 0; i < 16; i++) {
    int r = i * 4 + r0;   // row of the transposed output (n index)
    o[(size_t)(nb + r) * 1024 + kb + c] = f2bf(tile[c][r]);
  }
}

// ---------------------------------------------------------------- K1: xb = bf16(x * mask)
__global__ void xmask_kernel(const float* __restrict__ x, const int* __restrict__ mask,
                             unsigned short* __restrict__ xb) {
  const int idx = (blockIdx.x * 256 + threadIdx.x) * 4;  // 4 elems/thread
  const int row = idx >> 10;                             // b*T + t
  const float m = (float)mask[row];
  float4 v = *(const float4*)(x + idx);
  ushort4 o;
  o.x = f2bf(v.x * m);
  o.y = f2bf(v.y * m);
  o.z = f2bf(v.z * m);
  o.w = f2bf(v.w * m);
  *(ushort4*)(xb + idx) = o;
}

// ---------------------------------------------------------------- GEMM (m97 structure):
// C[m][n] = sum_k A[m][k] * Bt[n][k]. 128x128 tile, BK=32, 4 waves, global_load_lds.
// MODE: 0 = bf16 [m][n], 1 = f32 [m][n], 2 = bf16 V-transposed [(b*16+h)*64+u][t]
template <int MODE>
__device__ __forceinline__ void gemm97_body(const unsigned short* __restrict__ A,
                                            const unsigned short* __restrict__ Bt,
                                            void* __restrict__ Cout) {
  constexpr int Kd = 1024, Nd = 1024;
  __shared__ unsigned short la[128 * 32];  // linear [row][32k], 64B/row
  __shared__ unsigned short lb[128 * 32];
  const int tid = threadIdx.x;
  const int lane = tid & 63;
  const int w = tid >> 6;
  const int mb = blockIdx.y * 128, nb = blockIdx.x * 128;
  const int wm = (w >> 1) * 64, wn = (w & 1) * 64;
  const int lr = lane & 15, lg = lane >> 4;
  // staging map: per-wave LDS base (lane0) + lane*16B == srow*32 + scol for all lanes
  const int srow = w * 16 + (lane >> 2);     // 0..63 (+64 for second issue)
  const int scol = (lane & 3) * 8;
  const unsigned short* gA = A + (size_t)(mb + srow) * Kd + scol;
  const unsigned short* gB = Bt + (size_t)(nb + srow) * Kd + scol;
  unsigned short* lA = la + srow * 32 + scol;
  unsigned short* lB = lb + srow * 32 + scol;

  f32x4 acc[4][4] = {};

  for (int kt = 0; kt < Kd; kt += 32) {
    gld16(gA + kt, lA);
    gld16(gA + kt + (size_t)64 * Kd, lA + 64 * 32);
    gld16(gB + kt, lB);
    gld16(gB + kt + (size_t)64 * Kd, lB + 64 * 32);
    __syncthreads();  // vmcnt(0)+barrier: staged data visible to all waves
    s16x8 af[4], bfr[4];
#pragma unroll
    for (int i = 0; i < 4; i++)
      af[i] = *(const s16x8*)(la + (wm + i * 16 + lr) * 32 + lg * 8);
#pragma unroll
    for (int j = 0; j < 4; j++)
      bfr[j] = *(const s16x8*)(lb + (wn + j * 16 + lr) * 32 + lg * 8);
#pragma unroll
    for (int i = 0; i < 4; i++)
#pragma unroll
      for (int j = 0; j < 4; j++)
        acc[i][j] = mfma16(af[i], bfr[j], acc[i][j]);
    __syncthreads();  // all waves done reading before next stage overwrites
  }

  // epilogue: lane holds C[row = wm+i*16+lg*4+r][col = wn+j*16+lr]
#pragma unroll
  for (int i = 0; i < 4; i++)
#pragma unroll
    for (int j = 0; j < 4; j++) {
      const int col = nb + wn + j * 16 + lr;
      const int rowb = mb + wm + i * 16 + lg * 4;
      if (MODE == 1) {
        float* C = (float*)Cout;
#pragma unroll
        for (int r = 0; r < 4; r++) C[(size_t)(rowb + r) * Nd + col] = acc[i][j][r];
      } else if (MODE == 0) {
        unsigned short* C = (unsigned short*)Cout;
#pragma unroll
        for (int r = 0; r < 4; r++) C[(size_t)(rowb + r) * Nd + col] = f2bf(acc[i][j][r]);
      } else {
        // V-transposed: vt[((b*16+h)*64+u)][t], b=rowb>>11, t=rowb&2047, h=col>>6, u=col&63.
        unsigned short* C = (unsigned short*)Cout;
        const size_t vrow = ((size_t)(rowb >> 11) * 16 + (col >> 6)) * 64 + (col & 63);
        ushort4 o;
#pragma unroll
        for (int r = 0; r < 4; r++) ((unsigned short*)&o)[r] = f2bf(acc[i][j][r]);
        *(ushort4*)(C + vrow * T_ + (rowb & 2047)) = o;
      }
    }
}

__global__ __launch_bounds__(256) void gemm_qkv(const unsigned short* __restrict__ A,
                                                const unsigned short* __restrict__ wq,
                                                const unsigned short* __restrict__ wk,
                                                const unsigned short* __restrict__ wv,
                                                unsigned short* __restrict__ cq,
                                                unsigned short* __restrict__ ck,
                                                unsigned short* __restrict__ vt) {
  if (blockIdx.z == 0) {
    gemm97_body<0>(A, wq, cq);
  } else if (blockIdx.z == 1) {
    gemm97_body<0>(A, wk, ck);
  } else {
    gemm97_body<2>(A, wv, vt);  // writes V directly transposed
  }
}

__global__ __launch_bounds__(256) void gemm_out(const unsigned short* __restrict__ A,
                                                const unsigned short* __restrict__ woT,
                                                float* __restrict__ C) {
  gemm97_body<1>(A, woT, C);
}

// ---------------------------------------------------------------- K3: flash attention v8
// Block = (bh, 32 q-rows) with TWO waves splitting the j-tile sequence by parity.
// Each wave: attn5's proven per-tile math (L2-direct K/V, KVBLK=64, in-register
// online softmax). Partial (m,l,acc) merged once at the end via LDS (flash-combine).
__global__ __launch_bounds__(128, 4) void attn8_kernel(const unsigned short* __restrict__ Q,
                                                       const unsigned short* __restrict__ K,
                                                       const unsigned short* __restrict__ Vt,
                                                       const int* __restrict__ mask,
                                                       unsigned short* __restrict__ att) {
  __shared__ unsigned short pbuf[2][32 * 64];  // per-wave P repack, XOR-swizzled, 4KB each
  __shared__ float cb[36 * 64];                // combine buffer, element-major (conflict-free)
  const int tid = threadIdx.x;
  const int w = tid >> 6, lane = tid & 63;
  const int li = lane & 15, lg = lane >> 4;
  const int bh = blockIdx.x;
  const int b = bh >> 4, h = bh & 15;
  const int qg = 63 - blockIdx.y;          // longest-first dispatch
  const int q0 = qg * 32;

  const float CS = 0.125f * 1.44269504089f;   // 1/sqrt(U) * log2(e)
  const float PB = 10000.0f * 1.44269504089f; // pad bias, log2 domain

  s16x8 qf[2][2];
#pragma unroll
  for (int f = 0; f < 2; f++) {
    const unsigned short* qrow = Q + ((size_t)(b * T_) + q0 + f * 16 + li) * 1024 + h * 64;
    qf[f][0] = *(const s16x8*)(qrow + lg * 8);
    qf[f][1] = *(const s16x8*)(qrow + 32 + lg * 8);
  }

  const unsigned short* Kb = K + (size_t)(b * T_) * 1024 + h * 64;
  const unsigned short* Vtb = Vt + (size_t)bh * 64 * T_;
  const int* mk = mask + b * T_;

  const int iq0 = q0 + li, iq1 = q0 + 16 + li;

  float mrun[2] = {-1e30f, -1e30f}, lrun[2] = {0.f, 0.f};
  f32x4 acc[4][2] = {};  // [ufrag][ifrag]

  const int xr = (li & 3) << 5;
  char* pbb = (char*)&pbuf[w][0];

  const int ntiles = (q0 + 95) >> 6;  // ceil((q0+32)/64)
  for (int t = w; t < ntiles; t += 2) {   // j-split by parity across the 2 waves
    const int jb = t * 64;
    const bool diag = (jb + 64 > q0);  // wave-uniform

    // ---- K fragments + QK^T (swapped): s[jf][f], lane holds j=jb+jf*16+lg*4+r, i=q0+f*16+li
    f32x4 s[4][2] = {};
    __builtin_amdgcn_s_setprio(1);
#pragma unroll
    for (int jf = 0; jf < 4; jf++) {
      const unsigned short* kr = Kb + (size_t)(jb + jf * 16 + li) * 1024 + lg * 8;
      s16x8 ka = *(const s16x8*)kr;
      s16x8 kc = *(const s16x8*)(kr + 32);
      s[jf][0] = mfma16(ka, qf[0][0], s[jf][0]);
      s[jf][0] = mfma16(kc, qf[0][1], s[jf][0]);
      s[jf][1] = mfma16(ka, qf[1][0], s[jf][1]);
      s[jf][1] = mfma16(kc, qf[1][1], s[jf][1]);
    }
    __builtin_amdgcn_s_setprio(0);

    // ---- V fragments for this tile (independent loads; fly under softmax)
    s16x8 vf[4][2];
#pragma unroll
    for (int uf = 0; uf < 4; uf++) {
      const unsigned short* vr = Vtb + (size_t)(uf * 16 + li) * T_ + jb + lg * 8;
      vf[uf][0] = *(const s16x8*)vr;
      vf[uf][1] = *(const s16x8*)(vr + 32);
    }

    // ---- key padding bias, hoisted per tile (shared across ifrags)
    float bias[4][4];
#pragma unroll
    for (int jf = 0; jf < 4; jf++) {
      int4 mv = *(const int4*)(mk + jb + jf * 16 + lg * 4);
      bias[jf][0] = mv.x ? 0.f : -PB;
      bias[jf][1] = mv.y ? 0.f : -PB;
      bias[jf][2] = mv.z ? 0.f : -PB;
      bias[jf][3] = mv.w ? 0.f : -PB;
    }

    // ---- online softmax per ifrag (log2 domain)
#pragma unroll
    for (int f = 0; f < 2; f++) {
      const int iq = f ? iq1 : iq0;
      float pmax = -1e30f;
#pragma unroll
      for (int jf = 0; jf < 4; jf++) {
        f32x4 zz;
#pragma unroll
        for (int r = 0; r < 4; r++) {
          float z = fmaf(s[jf][f][r], CS, bias[jf][r]);
          if (diag && (jb + jf * 16 + lg * 4 + r > iq)) z = -1e30f;
          zz[r] = z;
          pmax = fmaxf(pmax, z);
        }
        s[jf][f] = zz;
      }
      pmax = fmaxf(pmax, __shfl_xor(pmax, 16));
      pmax = fmaxf(pmax, __shfl_xor(pmax, 32));
      if (!__all(pmax <= mrun[f])) {  // exact-skip rescale (alpha==1 when skipped)
        const float mnew = fmaxf(mrun[f], pmax);
        const float al = exp2f(mrun[f] - mnew);
        lrun[f] *= al;
#pragma unroll
        for (int uf = 0; uf < 4; uf++) acc[uf][f] *= al;
        mrun[f] = mnew;
      }
      const float mm = mrun[f];
      float psum = 0.f;
#pragma unroll
      for (int jf = 0; jf < 4; jf++) {
        ushort4 w4;
#pragma unroll
        for (int r = 0; r < 4; r++) {
          const float p = exp2f(s[jf][f][r] - mm);
          psum += p;
          ((unsigned short*)&w4)[r] = __builtin_bit_cast(unsigned short, (__bf16)p);
        }
        const int wb = (((f * 16 + li) * 64 + jf * 16 + lg * 4) * 2) ^ xr;
        *(ushort4*)(pbb + wb) = w4;
      }
      psum += __shfl_xor(psum, 16);
      psum += __shfl_xor(psum, 32);
      lrun[f] += psum;
    }

    // ---- PV (same-wave pbuf write->read; no cross-wave sharing)
    s16x8 pfrag[2][2];
#pragma unroll
    for (int f = 0; f < 2; f++)
#pragma unroll
      for (int hh = 0; hh < 2; hh++) {
        const int rd = (((f * 16 + li) * 64 + hh * 32 + lg * 8) * 2) ^ xr;
        pfrag[f][hh] = *(const s16x8*)(pbb + rd);
      }
    __builtin_amdgcn_s_setprio(1);
#pragma unroll
    for (int uf = 0; uf < 4; uf++)
#pragma unroll
      for (int f = 0; f < 2; f++) {
        acc[uf][f] = mfma16(vf[uf][0], pfrag[f][0], acc[uf][f]);
        acc[uf][f] = mfma16(vf[uf][1], pfrag[f][1], acc[uf][f]);
      }
    __builtin_amdgcn_s_setprio(0);
  }

  // ---- flash-combine of the two waves' partial states (one barrier)
  if (w == 1) {
#pragma unroll
    for (int f = 0; f < 2; f++)
#pragma unroll
      for (int uf = 0; uf < 4; uf++)
#pragma unroll
        for (int r = 0; r < 4; r++)
          cb[(f * 16 + uf * 4 + r) * 64 + lane] = acc[uf][f][r];
    cb[32 * 64 + lane] = mrun[0];
    cb[33 * 64 + lane] = mrun[1];
    cb[34 * 64 + lane] = lrun[0];
    cb[35 * 64 + lane] = lrun[1];
  }
  __syncthreads();
  if (w == 0) {
#pragma unroll
    for (int f = 0; f < 2; f++) {
      const float mB = cb[(32 + f) * 64 + lane];
      const float lB = cb[(34 + f) * 64 + lane];
      const float m = fmaxf(mrun[f], mB);
      const float aA = exp2f(mrun[f] - m);
      const float aB = exp2f(mB - m);
      const float inv = 1.0f / (aA * lrun[f] + aB * lB);
      unsigned short* arow = att + ((size_t)(b * T_) + q0 + f * 16 + li) * 1024 + h * 64;
#pragma unroll
      for (int uf = 0; uf < 4; uf++) {
        ushort4 o;
#pragma unroll
        for (int r = 0; r < 4; r++) {
          const float vB = cb[(f * 16 + uf * 4 + r) * 64 + lane];
          const float v = (aA * acc[uf][f][r] + aB * vB) * inv;
          ((unsigned short*)&o)[r] = __builtin_bit_cast(unsigned short, (__bf16)v);
        }
        *(ushort4*)(arow + uf * 16 + lg * 4) = o;
      }
    }
  }
}

// ----------------------------------------------------------------
extern "C" void kernel_launch(void* const* d_in, const int* in_sizes, int n_in,
                              void* d_out, int out_size, void* d_ws, size_t ws_size,
                              hipStream_t stream) {
  const float* x = (const float*)d_in[0];
  const int* mask = (const int*)d_in[1];
  const float* Wq = (const float*)d_in[2];
  const float* Wk = (const float*)d_in[3];
  const float* Wv = (const float*)d_in[4];
  const float* Wo = (const float*)d_in[5];

  const size_t MB = 1u << 20;
  char* ws = (char*)d_ws;
  unsigned short* wqT = (unsigned short*)(ws + 0 * MB);
  unsigned short* wkT = (unsigned short*)(ws + 2 * MB);
  unsigned short* wvT = (unsigned short*)(ws + 4 * MB);
  unsigned short* woT = (unsigned short*)(ws + 6 * MB);
  unsigned short* xb  = (unsigned short*)(ws + 8 * MB);   // 8MB; dead after gemm_qkv
  unsigned short* qb  = (unsigned short*)(ws + 16 * MB);  // 8MB
  unsigned short* kb  = (unsigned short*)(ws + 24 * MB);  // 8MB
  unsigned short* vt  = (unsigned short*)(ws + 32 * MB);  // 8MB, written transposed by gemm_qkv
  unsigned short* att = xb;                               // reuse xb slot (dead by attn time)
  (void)ws_size; (void)in_sizes; (void)n_in; (void)out_size;

  wtrans_kernel<<<dim3(16, 16, 4), 256, 0, stream>>>(Wq, Wk, Wv, Wo, wqT, wkT, wvT, woT);
  xmask_kernel<<<dim3(4096), 256, 0, stream>>>(x, mask, xb);
  gemm_qkv<<<dim3(8, 32, 3), 256, 0, stream>>>(xb, wqT, wkT, wvT, qb, kb, vt);
  attn8_kernel<<<dim3(32, 64), 128, 0, stream>>>(qb, kb, vt, mask, att);
  gemm_out<<<dim3(8, 32), 256, 0, stream>>>(att, woT, (float*)d_out);
}

// Round 8
// 175.892 us; speedup vs baseline: 1.4966x; 1.4966x over previous
//
#include <hip/hip_runtime.h>
#include <stdint.h>
#include <stddef.h>

#define B_ 2
#define T_ 2048
#define D_ 1024
#define H_ 16
#define U_ 64
#define M_ (B_ * T_)   // 4096
#define N_ (H_ * U_)   // 1024

typedef __attribute__((ext_vector_type(4))) float f32x4;
typedef __attribute__((ext_vector_type(8))) short s16x8;
typedef __attribute__((ext_vector_type(8))) __bf16 b16x8;

static_assert(sizeof(s16x8) == 16, "frag size");

__device__ __forceinline__ unsigned short f2bf(float f) {
  unsigned int u = __float_as_uint(f);
  u += 0x7FFFu + ((u >> 16) & 1u);     // RNE
  return (unsigned short)(u >> 16);
}

// --- MFMA wrapper: SFINAE hedge — works whether the builtin takes short8 or bf16x8
template <typename V>
__device__ __forceinline__ auto mfma16_impl(V a, V b, f32x4 c, int)
    -> decltype(__builtin_amdgcn_mfma_f32_16x16x32_bf16(a, b, c, 0, 0, 0)) {
  return __builtin_amdgcn_mfma_f32_16x16x32_bf16(a, b, c, 0, 0, 0);
}
template <typename V>
__device__ __forceinline__ f32x4 mfma16_impl(V a, V b, f32x4 c, long) {
  return __builtin_amdgcn_mfma_f32_16x16x32_bf16(
      __builtin_bit_cast(b16x8, a), __builtin_bit_cast(b16x8, b), c, 0, 0, 0);
}
__device__ __forceinline__ f32x4 mfma16(s16x8 a, s16x8 b, f32x4 c) {
  return mfma16_impl(a, b, c, 0);
}

// --- async global->LDS, 16B per lane (m97 lever)
__device__ __forceinline__ void gld16(const unsigned short* g, unsigned short* l) {
  __builtin_amdgcn_global_load_lds(
      (const __attribute__((address_space(1))) void*)g,
      (__attribute__((address_space(3))) void*)l, 16, 0, 0);
}

// ---------------------------------------------------------------- K0: W -> W^T (bf16)
__global__ void wtrans_kernel(const float* __restrict__ w0, const float* __restrict__ w1,
                              const float* __restrict__ w2, const float* __restrict__ w3,
                              unsigned short* __restrict__ o0, unsigned short* __restrict__ o1,
                              unsigned short* __restrict__ o2, unsigned short* __restrict__ o3) {
  __shared__ float tile[64][65];
  const float* w;
  unsigned short* o;
  switch (blockIdx.z) {
    case 0: w = w0; o = o0; break;
    case 1: w = w1; o = o1; break;
    case 2: w = w2; o = o2; break;
    default: w = w3; o = o3; break;
  }
  const int kb = blockIdx.y * 64, nb = blockIdx.x * 64;
  const int tid = threadIdx.x;
  const int r0 = tid >> 6, c = tid & 63;
#pragma unroll
  for (int i = 0; i < 16; i++) {
    int r = i * 4 + r0;
    tile[r][c] = w[(size_t)(kb + r) * 1024 + nb + c];
  }
  __syncthreads();
#pragma unroll
  for (int i = 0; i < 16; i++) {
    int r = i * 4 + r0;   // row of the transposed output (n index)
    o[(size_t)(nb + r) * 1024 + kb + c] = f2bf(tile[c][r]);
  }
}

// ---------------------------------------------------------------- K1: xb = bf16(x * mask)
__global__ void xmask_kernel(const float* __restrict__ x, const int* __restrict__ mask,
                             unsigned short* __restrict__ xb) {
  const int idx = (blockIdx.x * 256 + threadIdx.x) * 4;  // 4 elems/thread
  const int row = idx >> 10;                             // b*T + t
  const float m = (float)mask[row];
  float4 v = *(const float4*)(x + idx);
  ushort4 o;
  o.x = f2bf(v.x * m);
  o.y = f2bf(v.y * m);
  o.z = f2bf(v.z * m);
  o.w = f2bf(v.w * m);
  *(ushort4*)(xb + idx) = o;
}

// ---------------------------------------------------------------- GEMM (m97 structure):
// C[m][n] = sum_k A[m][k] * Bt[n][k]. 128x128 tile, BK=32, 4 waves, global_load_lds.
// MODE: 0 = bf16 [m][n], 1 = f32 [m][n], 2 = bf16 V-transposed [(b*16+h)*64+u][t]
template <int MODE>
__device__ __forceinline__ void gemm97_body(const unsigned short* __restrict__ A,
                                            const unsigned short* __restrict__ Bt,
                                            void* __restrict__ Cout) {
  constexpr int Kd = 1024, Nd = 1024;
  __shared__ unsigned short la[128 * 32];  // linear [row][32k], 64B/row
  __shared__ unsigned short lb[128 * 32];
  const int tid = threadIdx.x;
  const int lane = tid & 63;
  const int w = tid >> 6;
  const int mb = blockIdx.y * 128, nb = blockIdx.x * 128;
  const int wm = (w >> 1) * 64, wn = (w & 1) * 64;
  const int lr = lane & 15, lg = lane >> 4;
  // staging map: per-wave LDS base (lane0) + lane*16B == srow*32 + scol for all lanes
  const int srow = w * 16 + (lane >> 2);     // 0..63 (+64 for second issue)
  const int scol = (lane & 3) * 8;
  const unsigned short* gA = A + (size_t)(mb + srow) * Kd + scol;
  const unsigned short* gB = Bt + (size_t)(nb + srow) * Kd + scol;
  unsigned short* lA = la + srow * 32 + scol;
  unsigned short* lB = lb + srow * 32 + scol;

  f32x4 acc[4][4] = {};

  for (int kt = 0; kt < Kd; kt += 32) {
    gld16(gA + kt, lA);
    gld16(gA + kt + (size_t)64 * Kd, lA + 64 * 32);
    gld16(gB + kt, lB);
    gld16(gB + kt + (size_t)64 * Kd, lB + 64 * 32);
    __syncthreads();  // vmcnt(0)+barrier: staged data visible to all waves
    s16x8 af[4], bfr[4];
#pragma unroll
    for (int i = 0; i < 4; i++)
      af[i] = *(const s16x8*)(la + (wm + i * 16 + lr) * 32 + lg * 8);
#pragma unroll
    for (int j = 0; j < 4; j++)
      bfr[j] = *(const s16x8*)(lb + (wn + j * 16 + lr) * 32 + lg * 8);
#pragma unroll
    for (int i = 0; i < 4; i++)
#pragma unroll
      for (int j = 0; j < 4; j++)
        acc[i][j] = mfma16(af[i], bfr[j], acc[i][j]);
    __syncthreads();  // all waves done reading before next stage overwrites
  }

  // epilogue: lane holds C[row = wm+i*16+lg*4+r][col = wn+j*16+lr]
#pragma unroll
  for (int i = 0; i < 4; i++)
#pragma unroll
    for (int j = 0; j < 4; j++) {
      const int col = nb + wn + j * 16 + lr;
      const int rowb = mb + wm + i * 16 + lg * 4;
      if (MODE == 1) {
        float* C = (float*)Cout;
#pragma unroll
        for (int r = 0; r < 4; r++) C[(size_t)(rowb + r) * Nd + col] = acc[i][j][r];
      } else if (MODE == 0) {
        unsigned short* C = (unsigned short*)Cout;
#pragma unroll
        for (int r = 0; r < 4; r++) C[(size_t)(rowb + r) * Nd + col] = f2bf(acc[i][j][r]);
      } else {
        // V-transposed: vt[((b*16+h)*64+u)][t], b=rowb>>11, t=rowb&2047, h=col>>6, u=col&63.
        unsigned short* C = (unsigned short*)Cout;
        const size_t vrow = ((size_t)(rowb >> 11) * 16 + (col >> 6)) * 64 + (col & 63);
        ushort4 o;
#pragma unroll
        for (int r = 0; r < 4; r++) ((unsigned short*)&o)[r] = f2bf(acc[i][j][r]);
        *(ushort4*)(C + vrow * T_ + (rowb & 2047)) = o;
      }
    }
}

__global__ __launch_bounds__(256) void gemm_qkv(const unsigned short* __restrict__ A,
                                                const unsigned short* __restrict__ wq,
                                                const unsigned short* __restrict__ wk,
                                                const unsigned short* __restrict__ wv,
                                                unsigned short* __restrict__ cq,
                                                unsigned short* __restrict__ ck,
                                                unsigned short* __restrict__ vt) {
  if (blockIdx.z == 0) {
    gemm97_body<0>(A, wq, cq);
  } else if (blockIdx.z == 1) {
    gemm97_body<0>(A, wk, ck);
  } else {
    gemm97_body<2>(A, wv, vt);  // writes V directly transposed
  }
}

__global__ __launch_bounds__(256) void gemm_out(const unsigned short* __restrict__ A,
                                                const unsigned short* __restrict__ woT,
                                                float* __restrict__ C) {
  gemm97_body<1>(A, woT, C);
}

// ---------------------------------------------------------------- K3: flash attention v9
// Block = (bh, 32 q-rows) with TWO waves splitting the j-tile sequence by parity.
// NO forced occupancy bound: compiler allocates ~100 VGPR (no spill — R7's failure).
// Partial (m,l,acc) merged once at the end via LDS (flash-combine).
__global__ __launch_bounds__(128) void attn9_kernel(const unsigned short* __restrict__ Q,
                                                    const unsigned short* __restrict__ K,
                                                    const unsigned short* __restrict__ Vt,
                                                    const int* __restrict__ mask,
                                                    unsigned short* __restrict__ att) {
  __shared__ unsigned short pbuf[2][32 * 64];  // per-wave P repack, XOR-swizzled, 4KB each
  __shared__ float cb[36 * 64];                // combine buffer, element-major (conflict-free)
  const int tid = threadIdx.x;
  const int w = tid >> 6, lane = tid & 63;
  const int li = lane & 15, lg = lane >> 4;
  const int bh = blockIdx.x;
  const int b = bh >> 4, h = bh & 15;
  const int qg = 63 - blockIdx.y;          // longest-first dispatch
  const int q0 = qg * 32;

  const float CS = 0.125f * 1.44269504089f;   // 1/sqrt(U) * log2(e)
  const float PB = 10000.0f * 1.44269504089f; // pad bias, log2 domain

  s16x8 qf[2][2];
#pragma unroll
  for (int f = 0; f < 2; f++) {
    const unsigned short* qrow = Q + ((size_t)(b * T_) + q0 + f * 16 + li) * 1024 + h * 64;
    qf[f][0] = *(const s16x8*)(qrow + lg * 8);
    qf[f][1] = *(const s16x8*)(qrow + 32 + lg * 8);
  }

  const unsigned short* Kb = K + (size_t)(b * T_) * 1024 + h * 64;
  const unsigned short* Vtb = Vt + (size_t)bh * 64 * T_;
  const int* mk = mask + b * T_;

  const int iq0 = q0 + li, iq1 = q0 + 16 + li;

  float mrun[2] = {-1e30f, -1e30f}, lrun[2] = {0.f, 0.f};
  f32x4 acc[4][2] = {};  // [ufrag][ifrag]

  const int xr = (li & 3) << 5;
  char* pbb = (char*)&pbuf[w][0];

  const int ntiles = (q0 + 95) >> 6;  // ceil((q0+32)/64)
  for (int t = w; t < ntiles; t += 2) {   // j-split by parity across the 2 waves
    const int jb = t * 64;
    const bool diag = (jb + 64 > q0);  // wave-uniform

    // ---- K fragments + QK^T (swapped): s[jf][f], lane holds j=jb+jf*16+lg*4+r, i=q0+f*16+li
    f32x4 s[4][2] = {};
    __builtin_amdgcn_s_setprio(1);
#pragma unroll
    for (int jf = 0; jf < 4; jf++) {
      const unsigned short* kr = Kb + (size_t)(jb + jf * 16 + li) * 1024 + lg * 8;
      s16x8 ka = *(const s16x8*)kr;
      s16x8 kc = *(const s16x8*)(kr + 32);
      s[jf][0] = mfma16(ka, qf[0][0], s[jf][0]);
      s[jf][0] = mfma16(kc, qf[0][1], s[jf][0]);
      s[jf][1] = mfma16(ka, qf[1][0], s[jf][1]);
      s[jf][1] = mfma16(kc, qf[1][1], s[jf][1]);
    }
    __builtin_amdgcn_s_setprio(0);

    // ---- V fragments for this tile (independent loads; fly under softmax)
    s16x8 vf[4][2];
#pragma unroll
    for (int uf = 0; uf < 4; uf++) {
      const unsigned short* vr = Vtb + (size_t)(uf * 16 + li) * T_ + jb + lg * 8;
      vf[uf][0] = *(const s16x8*)vr;
      vf[uf][1] = *(const s16x8*)(vr + 32);
    }

    // ---- key padding bias, hoisted per tile (shared across ifrags)
    float bias[4][4];
#pragma unroll
    for (int jf = 0; jf < 4; jf++) {
      int4 mv = *(const int4*)(mk + jb + jf * 16 + lg * 4);
      bias[jf][0] = mv.x ? 0.f : -PB;
      bias[jf][1] = mv.y ? 0.f : -PB;
      bias[jf][2] = mv.z ? 0.f : -PB;
      bias[jf][3] = mv.w ? 0.f : -PB;
    }

    // ---- online softmax per ifrag (log2 domain)
#pragma unroll
    for (int f = 0; f < 2; f++) {
      const int iq = f ? iq1 : iq0;
      float pmax = -1e30f;
#pragma unroll
      for (int jf = 0; jf < 4; jf++) {
        f32x4 zz;
#pragma unroll
        for (int r = 0; r < 4; r++) {
          float z = fmaf(s[jf][f][r], CS, bias[jf][r]);
          if (diag && (jb + jf * 16 + lg * 4 + r > iq)) z = -1e30f;
          zz[r] = z;
          pmax = fmaxf(pmax, z);
        }
        s[jf][f] = zz;
      }
      pmax = fmaxf(pmax, __shfl_xor(pmax, 16));
      pmax = fmaxf(pmax, __shfl_xor(pmax, 32));
      if (!__all(pmax <= mrun[f])) {  // exact-skip rescale (alpha==1 when skipped)
        const float mnew = fmaxf(mrun[f], pmax);
        const float al = exp2f(mrun[f] - mnew);
        lrun[f] *= al;
#pragma unroll
        for (int uf = 0; uf < 4; uf++) acc[uf][f] *= al;
        mrun[f] = mnew;
      }
      const float mm = mrun[f];
      float psum = 0.f;
#pragma unroll
      for (int jf = 0; jf < 4; jf++) {
        ushort4 w4;
#pragma unroll
        for (int r = 0; r < 4; r++) {
          const float p = exp2f(s[jf][f][r] - mm);
          psum += p;
          ((unsigned short*)&w4)[r] = __builtin_bit_cast(unsigned short, (__bf16)p);
        }
        const int wb = (((f * 16 + li) * 64 + jf * 16 + lg * 4) * 2) ^ xr;
        *(ushort4*)(pbb + wb) = w4;
      }
      psum += __shfl_xor(psum, 16);
      psum += __shfl_xor(psum, 32);
      lrun[f] += psum;
    }

    // ---- PV (same-wave pbuf write->read; no cross-wave sharing)
    s16x8 pfrag[2][2];
#pragma unroll
    for (int f = 0; f < 2; f++)
#pragma unroll
      for (int hh = 0; hh < 2; hh++) {
        const int rd = (((f * 16 + li) * 64 + hh * 32 + lg * 8) * 2) ^ xr;
        pfrag[f][hh] = *(const s16x8*)(pbb + rd);
      }
    __builtin_amdgcn_s_setprio(1);
#pragma unroll
    for (int uf = 0; uf < 4; uf++)
#pragma unroll
      for (int f = 0; f < 2; f++) {
        acc[uf][f] = mfma16(vf[uf][0], pfrag[f][0], acc[uf][f]);
        acc[uf][f] = mfma16(vf[uf][1], pfrag[f][1], acc[uf][f]);
      }
    __builtin_amdgcn_s_setprio(0);
  }

  // ---- flash-combine of the two waves' partial states (one barrier)
  if (w == 1) {
#pragma unroll
    for (int f = 0; f < 2; f++)
#pragma unroll
      for (int uf = 0; uf < 4; uf++)
#pragma unroll
        for (int r = 0; r < 4; r++)
          cb[(f * 16 + uf * 4 + r) * 64 + lane] = acc[uf][f][r];
    cb[32 * 64 + lane] = mrun[0];
    cb[33 * 64 + lane] = mrun[1];
    cb[34 * 64 + lane] = lrun[0];
    cb[35 * 64 + lane] = lrun[1];
  }
  __syncthreads();
  if (w == 0) {
#pragma unroll
    for (int f = 0; f < 2; f++) {
      const float mB = cb[(32 + f) * 64 + lane];
      const float lB = cb[(34 + f) * 64 + lane];
      const float m = fmaxf(mrun[f], mB);
      const float aA = exp2f(mrun[f] - m);
      const float aB = exp2f(mB - m);
      const float inv = 1.0f / (aA * lrun[f] + aB * lB);
      unsigned short* arow = att + ((size_t)(b * T_) + q0 + f * 16 + li) * 1024 + h * 64;
#pragma unroll
      for (int uf = 0; uf < 4; uf++) {
        ushort4 o;
#pragma unroll
        for (int r = 0; r < 4; r++) {
          const float vB = cb[(f * 16 + uf * 4 + r) * 64 + lane];
          const float v = (aA * acc[uf][f][r] + aB * vB) * inv;
          ((unsigned short*)&o)[r] = __builtin_bit_cast(unsigned short, (__bf16)v);
        }
        *(ushort4*)(arow + uf * 16 + lg * 4) = o;
      }
    }
  }
}

// ----------------------------------------------------------------
extern "C" void kernel_launch(void* const* d_in, const int* in_sizes, int n_in,
                              void* d_out, int out_size, void* d_ws, size_t ws_size,
                              hipStream_t stream) {
  const float* x = (const float*)d_in[0];
  const int* mask = (const int*)d_in[1];
  const float* Wq = (const float*)d_in[2];
  const float* Wk = (const float*)d_in[3];
  const float* Wv = (const float*)d_in[4];
  const float* Wo = (const float*)d_in[5];

  const size_t MB = 1u << 20;
  char* ws = (char*)d_ws;
  unsigned short* wqT = (unsigned short*)(ws + 0 * MB);
  unsigned short* wkT = (unsigned short*)(ws + 2 * MB);
  unsigned short* wvT = (unsigned short*)(ws + 4 * MB);
  unsigned short* woT = (unsigned short*)(ws + 6 * MB);
  unsigned short* xb  = (unsigned short*)(ws + 8 * MB);   // 8MB; dead after gemm_qkv
  unsigned short* qb  = (unsigned short*)(ws + 16 * MB);  // 8MB
  unsigned short* kb  = (unsigned short*)(ws + 24 * MB);  // 8MB
  unsigned short* vt  = (unsigned short*)(ws + 32 * MB);  // 8MB, written transposed by gemm_qkv
  unsigned short* att = xb;                               // reuse xb slot (dead by attn time)
  (void)ws_size; (void)in_sizes; (void)n_in; (void)out_size;

  wtrans_kernel<<<dim3(16, 16, 4), 256, 0, stream>>>(Wq, Wk, Wv, Wo, wqT, wkT, wvT, woT);
  xmask_kernel<<<dim3(4096), 256, 0, stream>>>(x, mask, xb);
  gemm_qkv<<<dim3(8, 32, 3), 256, 0, stream>>>(xb, wqT, wkT, wvT, qb, kb, vt);
  attn9_kernel<<<dim3(32, 64), 128, 0, stream>>>(qb, kb, vt, mask, att);
  gemm_out<<<dim3(8, 32), 256, 0, stream>>>(att, woT, (float*)d_out);
}

// Round 9
// 154.738 us; speedup vs baseline: 1.7012x; 1.1367x over previous
//
#include <hip/hip_runtime.h>
#include <stdint.h>
#include <stddef.h>

#define B_ 2
#define T_ 2048
#define D_ 1024
#define H_ 16
#define U_ 64
#define M_ (B_ * T_)   // 4096
#define N_ (H_ * U_)   // 1024

typedef __attribute__((ext_vector_type(4))) float f32x4;
typedef __attribute__((ext_vector_type(8))) short s16x8;
typedef __attribute__((ext_vector_type(8))) __bf16 b16x8;

static_assert(sizeof(s16x8) == 16, "frag size");

__device__ __forceinline__ unsigned short f2bf(float f) {
  unsigned int u = __float_as_uint(f);
  u += 0x7FFFu + ((u >> 16) & 1u);     // RNE
  return (unsigned short)(u >> 16);
}

// --- MFMA wrapper: SFINAE hedge — works whether the builtin takes short8 or bf16x8
template <typename V>
__device__ __forceinline__ auto mfma16_impl(V a, V b, f32x4 c, int)
    -> decltype(__builtin_amdgcn_mfma_f32_16x16x32_bf16(a, b, c, 0, 0, 0)) {
  return __builtin_amdgcn_mfma_f32_16x16x32_bf16(a, b, c, 0, 0, 0);
}
template <typename V>
__device__ __forceinline__ f32x4 mfma16_impl(V a, V b, f32x4 c, long) {
  return __builtin_amdgcn_mfma_f32_16x16x32_bf16(
      __builtin_bit_cast(b16x8, a), __builtin_bit_cast(b16x8, b), c, 0, 0, 0);
}
__device__ __forceinline__ f32x4 mfma16(s16x8 a, s16x8 b, f32x4 c) {
  return mfma16_impl(a, b, c, 0);
}

// --- async global->LDS, 16B per lane (m97 lever)
__device__ __forceinline__ void gld16(const unsigned short* g, unsigned short* l) {
  __builtin_amdgcn_global_load_lds(
      (const __attribute__((address_space(1))) void*)g,
      (__attribute__((address_space(3))) void*)l, 16, 0, 0);
}

// ---------------------------------------------------------------- K0: W -> W^T (bf16)
__global__ void wtrans_kernel(const float* __restrict__ w0, const float* __restrict__ w1,
                              const float* __restrict__ w2, const float* __restrict__ w3,
                              unsigned short* __restrict__ o0, unsigned short* __restrict__ o1,
                              unsigned short* __restrict__ o2, unsigned short* __restrict__ o3) {
  __shared__ float tile[64][65];
  const float* w;
  unsigned short* o;
  switch (blockIdx.z) {
    case 0: w = w0; o = o0; break;
    case 1: w = w1; o = o1; break;
    case 2: w = w2; o = o2; break;
    default: w = w3; o = o3; break;
  }
  const int kb = blockIdx.y * 64, nb = blockIdx.x * 64;
  const int tid = threadIdx.x;
  const int r0 = tid >> 6, c = tid & 63;
#pragma unroll
  for (int i = 0; i < 16; i++) {
    int r = i * 4 + r0;
    tile[r][c] = w[(size_t)(kb + r) * 1024 + nb + c];
  }
  __syncthreads();
#pragma unroll
  for (int i = 0; i < 16; i++) {
    int r = i * 4 + r0;   // row of the transposed output (n index)
    o[(size_t)(nb + r) * 1024 + kb + c] = f2bf(tile[c][r]);
  }
}

// ---------------------------------------------------------------- K1: xb = bf16(x * mask)
__global__ void xmask_kernel(const float* __restrict__ x, const int* __restrict__ mask,
                             unsigned short* __restrict__ xb) {
  const int idx = (blockIdx.x * 256 + threadIdx.x) * 4;  // 4 elems/thread
  const int row = idx >> 10;                             // b*T + t
  const float m = (float)mask[row];
  float4 v = *(const float4*)(x + idx);
  ushort4 o;
  o.x = f2bf(v.x * m);
  o.y = f2bf(v.y * m);
  o.z = f2bf(v.z * m);
  o.w = f2bf(v.w * m);
  *(ushort4*)(xb + idx) = o;
}

// ---------------------------------------------------------------- GEMM (m97 structure):
// C[m][n] = sum_k A[m][k] * Bt[n][k]. 128x128 tile, BK=32, 4 waves, global_load_lds.
// MODE: 0 = bf16 [m][n], 1 = f32 [m][n], 2 = bf16 V-transposed [(b*16+h)*64+u][t]
template <int MODE>
__device__ __forceinline__ void gemm97_body(const unsigned short* __restrict__ A,
                                            const unsigned short* __restrict__ Bt,
                                            void* __restrict__ Cout) {
  constexpr int Kd = 1024, Nd = 1024;
  __shared__ unsigned short la[128 * 32];  // linear [row][32k], 64B/row
  __shared__ unsigned short lb[128 * 32];
  const int tid = threadIdx.x;
  const int lane = tid & 63;
  const int w = tid >> 6;
  const int mb = blockIdx.y * 128, nb = blockIdx.x * 128;
  const int wm = (w >> 1) * 64, wn = (w & 1) * 64;
  const int lr = lane & 15, lg = lane >> 4;
  // staging map: per-wave LDS base (lane0) + lane*16B == srow*32 + scol for all lanes
  const int srow = w * 16 + (lane >> 2);     // 0..63 (+64 for second issue)
  const int scol = (lane & 3) * 8;
  const unsigned short* gA = A + (size_t)(mb + srow) * Kd + scol;
  const unsigned short* gB = Bt + (size_t)(nb + srow) * Kd + scol;
  unsigned short* lA = la + srow * 32 + scol;
  unsigned short* lB = lb + srow * 32 + scol;

  f32x4 acc[4][4] = {};

  for (int kt = 0; kt < Kd; kt += 32) {
    gld16(gA + kt, lA);
    gld16(gA + kt + (size_t)64 * Kd, lA + 64 * 32);
    gld16(gB + kt, lB);
    gld16(gB + kt + (size_t)64 * Kd, lB + 64 * 32);
    __syncthreads();  // vmcnt(0)+barrier: staged data visible to all waves
    s16x8 af[4], bfr[4];
#pragma unroll
    for (int i = 0; i < 4; i++)
      af[i] = *(const s16x8*)(la + (wm + i * 16 + lr) * 32 + lg * 8);
#pragma unroll
    for (int j = 0; j < 4; j++)
      bfr[j] = *(const s16x8*)(lb + (wn + j * 16 + lr) * 32 + lg * 8);
#pragma unroll
    for (int i = 0; i < 4; i++)
#pragma unroll
      for (int j = 0; j < 4; j++)
        acc[i][j] = mfma16(af[i], bfr[j], acc[i][j]);
    __syncthreads();  // all waves done reading before next stage overwrites
  }

  // epilogue: lane holds C[row = wm+i*16+lg*4+r][col = wn+j*16+lr]
#pragma unroll
  for (int i = 0; i < 4; i++)
#pragma unroll
    for (int j = 0; j < 4; j++) {
      const int col = nb + wn + j * 16 + lr;
      const int rowb = mb + wm + i * 16 + lg * 4;
      if (MODE == 1) {
        float* C = (float*)Cout;
#pragma unroll
        for (int r = 0; r < 4; r++) C[(size_t)(rowb + r) * Nd + col] = acc[i][j][r];
      } else if (MODE == 0) {
        unsigned short* C = (unsigned short*)Cout;
#pragma unroll
        for (int r = 0; r < 4; r++) C[(size_t)(rowb + r) * Nd + col] = f2bf(acc[i][j][r]);
      } else {
        // V-transposed: vt[((b*16+h)*64+u)][t], b=rowb>>11, t=rowb&2047, h=col>>6, u=col&63.
        unsigned short* C = (unsigned short*)Cout;
        const size_t vrow = ((size_t)(rowb >> 11) * 16 + (col >> 6)) * 64 + (col & 63);
        ushort4 o;
#pragma unroll
        for (int r = 0; r < 4; r++) ((unsigned short*)&o)[r] = f2bf(acc[i][j][r]);
        *(ushort4*)(C + vrow * T_ + (rowb & 2047)) = o;
      }
    }
}

__global__ __launch_bounds__(256) void gemm_qkv(const unsigned short* __restrict__ A,
                                                const unsigned short* __restrict__ wq,
                                                const unsigned short* __restrict__ wk,
                                                const unsigned short* __restrict__ wv,
                                                unsigned short* __restrict__ cq,
                                                unsigned short* __restrict__ ck,
                                                unsigned short* __restrict__ vt) {
  if (blockIdx.z == 0) {
    gemm97_body<0>(A, wq, cq);
  } else if (blockIdx.z == 1) {
    gemm97_body<0>(A, wk, ck);
  } else {
    gemm97_body<2>(A, wv, vt);  // writes V directly transposed
  }
}

__global__ __launch_bounds__(256) void gemm_out(const unsigned short* __restrict__ A,
                                                const unsigned short* __restrict__ woT,
                                                float* __restrict__ C) {
  gemm97_body<1>(A, woT, C);
}

// ---------------------------------------------------------------- K3: flash attention v10
// attn5 structure (1 wave per 32 q-rows, KVBLK=64, L2-direct K/V) with a
// SHUFFLE-FREE common-path softmax:
//  - defer-max (THR=8, log2 domain): per-lane partial pmax + __all check;
//    cross-lane reduce + rescale only when triggered (~first tile only)
//  - deferred psum: per-lane partial lpart, reduced once at epilogue
//  - mask loads hoisted above QK^T MFMAs
__global__ __launch_bounds__(64) void attn10_kernel(const unsigned short* __restrict__ Q,
                                                    const unsigned short* __restrict__ K,
                                                    const unsigned short* __restrict__ Vt,
                                                    const int* __restrict__ mask,
                                                    unsigned short* __restrict__ att) {
  __shared__ unsigned short pbuf[32 * 64];  // P repack, XOR-swizzled, 4KB
  const int lane = threadIdx.x & 63;
  const int li = lane & 15, lg = lane >> 4;
  const int bh = blockIdx.x;
  const int b = bh >> 4, h = bh & 15;
  const int qg = 63 - blockIdx.y;          // longest-first dispatch
  const int q0 = qg * 32;

  const float CS = 0.125f * 1.44269504089f;   // 1/sqrt(U) * log2(e)
  const float PB = 10000.0f * 1.44269504089f; // pad bias, log2 domain
  const float THR = 8.0f;                     // defer-max threshold (log2 domain)

  s16x8 qf[2][2];
#pragma unroll
  for (int f = 0; f < 2; f++) {
    const unsigned short* qrow = Q + ((size_t)(b * T_) + q0 + f * 16 + li) * 1024 + h * 64;
    qf[f][0] = *(const s16x8*)(qrow + lg * 8);
    qf[f][1] = *(const s16x8*)(qrow + 32 + lg * 8);
  }

  const unsigned short* Kb = K + (size_t)(b * T_) * 1024 + h * 64;
  const unsigned short* Vtb = Vt + (size_t)bh * 64 * T_;
  const int* mk = mask + b * T_;

  const int iq0 = q0 + li, iq1 = q0 + 16 + li;

  float mrun[2] = {-1e30f, -1e30f};
  float lpart[2] = {0.f, 0.f};   // per-lane partial row-sums (reduced at epilogue)
  f32x4 acc[4][2] = {};          // [ufrag][ifrag]

  const int xr = (li & 3) << 5;
  char* pbb = (char*)pbuf;

  const int ntiles = (q0 + 95) >> 6;  // ceil((q0+32)/64)
  for (int t = 0; t < ntiles; t++) {
    const int jb = t * 64;
    const bool diag = (jb + 64 > q0);  // wave-uniform

    // ---- mask words first: latency flies under QK^T MFMAs
    int4 mv[4];
#pragma unroll
    for (int jf = 0; jf < 4; jf++)
      mv[jf] = *(const int4*)(mk + jb + jf * 16 + lg * 4);

    // ---- K fragments + QK^T (swapped): s[jf][f], lane holds j=jb+jf*16+lg*4+r, i=q0+f*16+li
    f32x4 s[4][2] = {};
#pragma unroll
    for (int jf = 0; jf < 4; jf++) {
      const unsigned short* kr = Kb + (size_t)(jb + jf * 16 + li) * 1024 + lg * 8;
      s16x8 ka = *(const s16x8*)kr;
      s16x8 kc = *(const s16x8*)(kr + 32);
      s[jf][0] = mfma16(ka, qf[0][0], s[jf][0]);
      s[jf][0] = mfma16(kc, qf[0][1], s[jf][0]);
      s[jf][1] = mfma16(ka, qf[1][0], s[jf][1]);
      s[jf][1] = mfma16(kc, qf[1][1], s[jf][1]);
    }

    // ---- V fragments for this tile (independent loads; fly under softmax)
    s16x8 vf[4][2];
#pragma unroll
    for (int uf = 0; uf < 4; uf++) {
      const unsigned short* vr = Vtb + (size_t)(uf * 16 + li) * T_ + jb + lg * 8;
      vf[uf][0] = *(const s16x8*)vr;
      vf[uf][1] = *(const s16x8*)(vr + 32);
    }

    // ---- key padding bias from the preloaded mask words
    float bias[4][4];
#pragma unroll
    for (int jf = 0; jf < 4; jf++) {
      bias[jf][0] = mv[jf].x ? 0.f : -PB;
      bias[jf][1] = mv[jf].y ? 0.f : -PB;
      bias[jf][2] = mv[jf].z ? 0.f : -PB;
      bias[jf][3] = mv[jf].w ? 0.f : -PB;
    }

    // ---- softmax per ifrag: shuffle-free common path
#pragma unroll
    for (int f = 0; f < 2; f++) {
      const int iq = f ? iq1 : iq0;
      float pmax = -3e38f;   // per-LANE partial max (no cross-lane reduce)
#pragma unroll
      for (int jf = 0; jf < 4; jf++) {
        f32x4 zz;
#pragma unroll
        for (int r = 0; r < 4; r++) {
          float z = fmaf(s[jf][f][r], CS, bias[jf][r]);
          if (diag && (jb + jf * 16 + lg * 4 + r > iq)) z = -1e30f;
          zz[r] = z;
          pmax = fmaxf(pmax, z);
        }
        s[jf][f] = zz;
      }
      // defer-max: rescale only if some lane exceeds mrun+THR (rare after tile 0)
      if (!__all(pmax <= mrun[f] + THR)) {
        float rmax = fmaxf(pmax, __shfl_xor(pmax, 16));
        rmax = fmaxf(rmax, __shfl_xor(rmax, 32));
        const float mnew = fmaxf(mrun[f], rmax);
        const float al = exp2f(mrun[f] - mnew);
        lpart[f] *= al;
#pragma unroll
        for (int uf = 0; uf < 4; uf++) acc[uf][f] *= al;
        mrun[f] = mnew;
      }
      const float mm = mrun[f];
#pragma unroll
      for (int jf = 0; jf < 4; jf++) {
        ushort4 w4;
#pragma unroll
        for (int r = 0; r < 4; r++) {
          const float p = exp2f(s[jf][f][r] - mm);  // bounded by 2^THR
          lpart[f] += p;
          ((unsigned short*)&w4)[r] = __builtin_bit_cast(unsigned short, (__bf16)p);
        }
        const int wb = (((f * 16 + li) * 64 + jf * 16 + lg * 4) * 2) ^ xr;
        *(ushort4*)(pbb + wb) = w4;
      }
    }

    // ---- PV (same-wave pbuf write->read; single wave per block)
    s16x8 pfrag[2][2];
#pragma unroll
    for (int f = 0; f < 2; f++)
#pragma unroll
      for (int hh = 0; hh < 2; hh++) {
        const int rd = (((f * 16 + li) * 64 + hh * 32 + lg * 8) * 2) ^ xr;
        pfrag[f][hh] = *(const s16x8*)(pbb + rd);
      }
#pragma unroll
    for (int uf = 0; uf < 4; uf++)
#pragma unroll
      for (int f = 0; f < 2; f++) {
        acc[uf][f] = mfma16(vf[uf][0], pfrag[f][0], acc[uf][f]);
        acc[uf][f] = mfma16(vf[uf][1], pfrag[f][1], acc[uf][f]);
      }
  }

  // ---- epilogue: reduce lpart once, then normalize + store
#pragma unroll
  for (int f = 0; f < 2; f++) {
    float l = lpart[f];
    l += __shfl_xor(l, 16);
    l += __shfl_xor(l, 32);
    const float inv = 1.0f / l;
    unsigned short* arow = att + ((size_t)(b * T_) + q0 + f * 16 + li) * 1024 + h * 64;
#pragma unroll
    for (int uf = 0; uf < 4; uf++) {
      ushort4 o;
#pragma unroll
      for (int r = 0; r < 4; r++)
        ((unsigned short*)&o)[r] = __builtin_bit_cast(unsigned short, (__bf16)(acc[uf][f][r] * inv));
      *(ushort4*)(arow + uf * 16 + lg * 4) = o;
    }
  }
}

// ----------------------------------------------------------------
extern "C" void kernel_launch(void* const* d_in, const int* in_sizes, int n_in,
                              void* d_out, int out_size, void* d_ws, size_t ws_size,
                              hipStream_t stream) {
  const float* x = (const float*)d_in[0];
  const int* mask = (const int*)d_in[1];
  const float* Wq = (const float*)d_in[2];
  const float* Wk = (const float*)d_in[3];
  const float* Wv = (const float*)d_in[4];
  const float* Wo = (const float*)d_in[5];

  const size_t MB = 1u << 20;
  char* ws = (char*)d_ws;
  unsigned short* wqT = (unsigned short*)(ws + 0 * MB);
  unsigned short* wkT = (unsigned short*)(ws + 2 * MB);
  unsigned short* wvT = (unsigned short*)(ws + 4 * MB);
  unsigned short* woT = (unsigned short*)(ws + 6 * MB);
  unsigned short* xb  = (unsigned short*)(ws + 8 * MB);   // 8MB; dead after gemm_qkv
  unsigned short* qb  = (unsigned short*)(ws + 16 * MB);  // 8MB
  unsigned short* kb  = (unsigned short*)(ws + 24 * MB);  // 8MB
  unsigned short* vt  = (unsigned short*)(ws + 32 * MB);  // 8MB, written transposed by gemm_qkv
  unsigned short* att = xb;                               // reuse xb slot (dead by attn time)
  (void)ws_size; (void)in_sizes; (void)n_in; (void)out_size;

  wtrans_kernel<<<dim3(16, 16, 4), 256, 0, stream>>>(Wq, Wk, Wv, Wo, wqT, wkT, wvT, woT);
  xmask_kernel<<<dim3(4096), 256, 0, stream>>>(x, mask, xb);
  gemm_qkv<<<dim3(8, 32, 3), 256, 0, stream>>>(xb, wqT, wkT, wvT, qb, kb, vt);
  attn10_kernel<<<dim3(32, 64), 64, 0, stream>>>(qb, kb, vt, mask, att);
  gemm_out<<<dim3(8, 32), 256, 0, stream>>>(att, woT, (float*)d_out);
}